// Round 12
// baseline (119.523 us; speedup 1.0000x reference)
//
#include <hip/hip_runtime.h>
#include <math.h>

#define BB 2
#define SS 2048
#define HH 1024
#define NH 16
#define HD 64
#define MM (BB*SS)   // 4096

typedef __attribute__((ext_vector_type(8))) _Float16 f16x8;
typedef __attribute__((ext_vector_type(2))) __fp16 hf16x2;
typedef __attribute__((ext_vector_type(4))) float f32x4;

// 0.125 (1/sqrt(64)) * log2(e), folded into Q at the projection epilogue
#define QSCALE 0.18033688011112042f

__device__ __forceinline__ unsigned short f2h(float f) {
    union { _Float16 h; unsigned short u; } c;
    c.h = (_Float16)f;
    return c.u;
}

// pack two floats to fp16x2 (RTZ) -> raw u32
__device__ __forceinline__ unsigned int pkh(float a, float b) {
    union { hf16x2 h; unsigned int u; } c;
    c.h = __builtin_amdgcn_cvt_pkrtz(a, b);
    return c.u;
}

__device__ __forceinline__ void gld16(const void* g, void* s) {
    __builtin_amdgcn_global_load_lds(
        (const __attribute__((address_space(1))) void*)g,
        (__attribute__((address_space(3))) void*)s, 16, 0, 0);
}

// ---------------- prep: cast x/W to fp16 + RoPE/mask tables + mask flags ----------------
__global__ __launch_bounds__(256) void prep(
    const float* __restrict__ x, const float* __restrict__ mask,
    const float* __restrict__ Wq, const float* __restrict__ Wk,
    const float* __restrict__ Wv, const float* __restrict__ Wo,
    unsigned short* __restrict__ xf, unsigned short* __restrict__ wf,
    float* __restrict__ ctab, float* __restrict__ stab, float* __restrict__ mt,
    unsigned int* __restrict__ mflag)
{
    int gtid = blockIdx.x * 256 + threadIdx.x;      // 2048*256 = 524288 threads
    if (gtid < SS * 32) {                            // RoPE table, f64 trig
        int s = gtid >> 5, i = gtid & 31;
        double invf = pow(10000.0, -(double)i / 32.0);
        double a = (double)s * invf;
        ctab[gtid] = (float)cos(a);
        stab[gtid] = (float)sin(a);
    }
    if (gtid < BB * SS) {                            // additive mask table (exp2 domain)
        float mv = mask[gtid];
        mt[gtid] = (1.0f - mv) * (-1.0e38f);
        // per-(b, 64k-tile) all-ones flag: one ballot per wave, lane0 stores
        unsigned long long bal = __ballot(mv == 1.0f);
        if ((threadIdx.x & 63) == 0)
            mflag[gtid >> 6] = (bal == ~0ull) ? 1u : 0u;
    }
    for (int it = gtid; it < 2097152; it += 524288) {   // 2M float4 items
        float4 v; unsigned short* d; size_t off;
        if (it < 1048576) {                              // x: [4096][1024]
            off = (size_t)it * 4;
            v = *(const float4*)(x + off);
            d = xf;
        } else {                                         // W concat rows: Wq,Wk,Wv,Wo
            off = (size_t)(it - 1048576) * 4;
            int row = (int)(off >> 10);
            const float* W = row < 1024 ? Wq : row < 2048 ? Wk : row < 3072 ? Wv : Wo;
            v = *(const float4*)(W + (((size_t)(row & 1023)) << 10) + (off & 1023));
            d = wf;
        }
        *(ushort4*)(d + off) = make_ushort4(f2h(v.x), f2h(v.y), f2h(v.z), f2h(v.w));
    }
}

// ---------------- fp16 MFMA GEMM (128x128 tile, BK=32, dbuf 32KB) ----------------
// (unchanged from round 11 — verified 0 conflicts, 2-phase dbuf)
template<int MODE>
__global__ __launch_bounds__(256, 3) void gemm3(
    const unsigned short* __restrict__ Axf,
    const unsigned short* __restrict__ Wf,
    const float* __restrict__ ctab, const float* __restrict__ stab,
    unsigned short* __restrict__ qo, unsigned short* __restrict__ ko,
    unsigned short* __restrict__ vo, float* __restrict__ fout)
{
    __shared__ __align__(16) short lsA[2][128*32];
    __shared__ __align__(16) short lsB[2][128*32];

    const int t = threadIdx.x;
    const int m0 = blockIdx.x * 128;
    const int brow0 = (MODE == 0 ? 0 : 3072) + blockIdx.y * 128;
    const int lane = t & 63, wv = t >> 6;
    const int wm = (wv >> 1) * 64, wn = (wv & 1) * 64;
    const int fr = lane & 15, fg = lane >> 4;

    const int srow = t >> 2, pc = t & 3;
    const int scx = (pc ^ ((srow >> 1) & 3)) * 8;     // source col offset (shorts)
    const int lo  = srow * 32 + pc * 8;               // physical dest (shorts)
    const size_t gA0 = (size_t)(m0 + srow) * HH + scx;
    const size_t gA1 = (size_t)(m0 + 64 + srow) * HH + scx;
    const size_t gB0 = (size_t)(brow0 + srow) * HH + scx;
    const size_t gB1 = (size_t)(brow0 + 64 + srow) * HH + scx;

    f32x4 acc[4][4] = {};

#define STAGE(sel, kk) do { \
        gld16(Axf + gA0 + (kk), &lsA[sel][lo]);            \
        gld16(Wf  + gB0 + (kk), &lsB[sel][lo]);            \
        gld16(Axf + gA1 + (kk), &lsA[sel][lo + 64*32]);    \
        gld16(Wf  + gB1 + (kk), &lsB[sel][lo + 64*32]);    \
    } while (0)

    STAGE(0, 0);
    __syncthreads();

    int cur = 0;
    for (int k0 = 0; k0 < HH; k0 += 32) {
        if (k0 + 32 < HH) STAGE(cur ^ 1, k0 + 32);

        f16x8 ah[4], bh[4];
        const int swz = (fg ^ ((fr >> 1) & 3)) * 8;   // swizzled read granule
        #pragma unroll
        for (int mi = 0; mi < 4; ++mi)
            ah[mi] = *(const f16x8*)&lsA[cur][(wm + 16*mi + fr)*32 + swz];
        #pragma unroll
        for (int ni = 0; ni < 4; ++ni)
            bh[ni] = *(const f16x8*)&lsB[cur][(wn + 16*ni + fr)*32 + swz];

        __builtin_amdgcn_s_setprio(1);
        #pragma unroll
        for (int mi = 0; mi < 4; ++mi)
            #pragma unroll
            for (int ni = 0; ni < 4; ++ni)
                acc[mi][ni] = __builtin_amdgcn_mfma_f32_16x16x32_f16(ah[mi], bh[ni], acc[mi][ni], 0, 0, 0);
        __builtin_amdgcn_s_setprio(0);
        __syncthreads();
        cur ^= 1;
    }
#undef STAGE

    if (MODE == 0) {
        const int mat = brow0 >> 10;                 // 0=Q 1=K 2=V
        const int obase = (brow0 & 1023) + wn;       // 64-aligned
        const int h = obase >> 6;
        #pragma unroll
        for (int mi = 0; mi < 4; ++mi)
            #pragma unroll
            for (int rr = 0; rr < 4; ++rr) {
                int m = m0 + wm + 16*mi + 4*fg + rr;
                int b = m >> 11, s = m & (SS - 1);
                float v[4];
                #pragma unroll
                for (int ni = 0; ni < 4; ++ni) v[ni] = acc[mi][ni][rr];
                if (mat < 2) {                        // RoPE on Q,K
                    #pragma unroll
                    for (int ni = 0; ni < 2; ++ni) {
                        int i = 16*ni + fr;
                        float c = ctab[s*32 + i], sn = stab[s*32 + i];
                        float v1 = v[ni], v2 = v[ni + 2];
                        v[ni]     = v1*c - v2*sn;
                        v[ni + 2] = v2*c + v1*sn;
                    }
                }
                if (mat == 0) {                       // fold softmax scale into Q
                    #pragma unroll
                    for (int ni = 0; ni < 4; ++ni) v[ni] *= QSCALE;
                }
                size_t base = ((size_t)(b*NH + h) * SS + s) * HD;
                #pragma unroll
                for (int ni = 0; ni < 4; ++ni) {
                    int d = 16*ni + fr;
                    unsigned short hb = f2h(v[ni]);
                    if (mat == 0)      qo[base + d] = hb;
                    else if (mat == 1) ko[base + (d ^ ((s & 7) << 3))] = hb;
                    else {
                        size_t va = ((size_t)(b*NH + h) * HD + d) * SS
                                  + (s & ~63) + ((s & 63) ^ ((d & 7) << 3));
                        vo[va] = hb;
                    }
                }
            }
    } else {
        const int n0 = blockIdx.y * 128 + wn;
        #pragma unroll
        for (int mi = 0; mi < 4; ++mi)
            #pragma unroll
            for (int rr = 0; rr < 4; ++rr) {
                int m = m0 + wm + 16*mi + 4*fg + rr;
                #pragma unroll
                for (int ni = 0; ni < 4; ++ni)
                    fout[(size_t)m * HH + n0 + 16*ni + fr] = acc[mi][ni][rr];
            }
    }
}

// ---------------- flash attention, k-sliced waves ----------------
// Grid 512 XCD-swizzled, 256 threads = 4 waves: wave (kh=wv>>1, qh=wv&1)
// owns k-slice [32kh,32kh+32) x q-half [64qh,64qh+64) of each 64k x 128q tile.
// K-frag and V-frag LDS reads cover only the wave's 32-k slice -> block-level
// K/V fragment traffic HALVES vs round 11 (which was LDS-pipe-bound at ~68%).
// S^T = mfma(K,Q) per slice; P -> Ps[q 128][k 64] (row-XOR swizzled, fully
// wave-private: qh picks rows, kh picks column half); O^T partial over k-slice
// accumulated across all tiles; single cross-wave (kh) sum at epilogue.
// Row-sum lpart via VALU adds (ones-MFMA removed).
__global__ __launch_bounds__(256, 2) void attn(
    const unsigned short* __restrict__ qg, const unsigned short* __restrict__ kg,
    const unsigned short* __restrict__ vtg, const float* __restrict__ mt,
    const unsigned int* __restrict__ mfl, unsigned short* __restrict__ cf)
{
    __shared__ __align__(16) short Ks[2][64*64];
    __shared__ __align__(16) short Vs[2][64*64];
    __shared__ __align__(16) short Ps[128*64];   // P tiles; f32 scratch in epilogue

    const int t = threadIdx.x, lane = t & 63, wv = t >> 6;   // wv 0..3
    const int fr = lane & 15, fg = lane >> 4, frx = fr & 7;
    const int qh = wv & 1, kh = wv >> 1;
    const int flat = blockIdx.x;
    const int bh = (flat & 7) + ((flat >> 7) << 3);          // XCD-grouped
    const int q0 = ((flat >> 3) & 15) * 128;
    const int b = bh >> 4, h = bh & 15;

    const unsigned short* kgb = kg  + (size_t)bh*SS*HD;
    const unsigned short* vgb = vtg + (size_t)bh*HD*SS;
    const float* mtb = mt + (size_t)b*SS;
    const unsigned int* mfb = mfl + b*32;

    // Q B-frags (regs, QSCALE pre-folded): qa[qf][dc] = Q[q0+64qh+16qf+fr][32dc+8fg+:8]
    f16x8 qa[4][2];
    #pragma unroll
    for (int qf = 0; qf < 4; ++qf)
        #pragma unroll
        for (int dc = 0; dc < 2; ++dc)
            qa[qf][dc] = *(const f16x8*)&qg[((size_t)bh*SS + q0 + 64*qh + 16*qf + fr)*HD + 32*dc + 8*fg];

    f32x4 o[4][4] = {};              // [df][qf] k-partial O^T
    float lpart[4] = {0.f, 0.f, 0.f, 0.f};

    const int srow = t >> 3, sg = t & 7;   // staging: 32 rows x 8 granules (x2)

    // prologue: stage tile 0
    gld16(kgb + (size_t)srow*HD + sg*8,      &Ks[0][srow*64 + sg*8]);
    gld16(kgb + (size_t)(32+srow)*HD + sg*8, &Ks[0][(32+srow)*64 + sg*8]);
    gld16(vgb + (size_t)srow*SS + sg*8,      &Vs[0][srow*64 + sg*8]);
    gld16(vgb + (size_t)(32+srow)*SS + sg*8, &Vs[0][(32+srow)*64 + sg*8]);
    __syncthreads();

    int cur = 0;
    for (int kt = 0; kt < SS/64; ++kt) {
        const int k0 = kt * 64;
        if (kt + 1 < SS/64) {                 // prefetch next tile
            const int kn = k0 + 64;
            gld16(kgb + (size_t)(kn+srow)*HD + sg*8,      &Ks[cur^1][srow*64 + sg*8]);
            gld16(kgb + (size_t)(kn+32+srow)*HD + sg*8,   &Ks[cur^1][(32+srow)*64 + sg*8]);
            gld16(vgb + (size_t)srow*SS + kn + sg*8,      &Vs[cur^1][srow*64 + sg*8]);
            gld16(vgb + (size_t)(32+srow)*SS + kn + sg*8, &Vs[cur^1][(32+srow)*64 + sg*8]);
        }
        const int fl = __builtin_amdgcn_readfirstlane(mfb[kt]);

        // S^T = K Q^T over this wave's 32-k slice (K-frags: own slice only)
        f16x8 kb[2][2];
        #pragma unroll
        for (int nk = 0; nk < 2; ++nk)
            #pragma unroll
            for (int dc = 0; dc < 2; ++dc)
                kb[nk][dc] = *(const f16x8*)&Ks[cur][(32*kh + 16*nk + fr)*64 + (((4*dc + fg) ^ frx) * 8)];

        f32x4 sc[2][4] = {};
        __builtin_amdgcn_s_setprio(1);
        #pragma unroll
        for (int dc = 0; dc < 2; ++dc)
            #pragma unroll
            for (int nk = 0; nk < 2; ++nk)
                #pragma unroll
                for (int qf = 0; qf < 4; ++qf)
                    sc[nk][qf] = __builtin_amdgcn_mfma_f32_16x16x32_f16(kb[nk][dc], qa[qf][dc], sc[nk][qf], 0, 0, 0);
        __builtin_amdgcn_s_setprio(0);

        // P = 2^(s [+ madd]); write to Ps[q][k] (wave-private rows/cols)
        #pragma unroll
        for (int nk = 0; nk < 2; ++nk) {
            float4 m4;
            if (!fl) m4 = *(const float4*)&mtb[k0 + 32*kh + 16*nk + 4*fg];
            const int pgw = ((4*kh + 2*nk + (fg >> 1)) ^ frx) * 8 + 4*(fg & 1);
            #pragma unroll
            for (int qf = 0; qf < 4; ++qf) {
                float p0, p1, p2, p3;
                if (fl) {
                    p0 = __builtin_amdgcn_exp2f(sc[nk][qf][0]);
                    p1 = __builtin_amdgcn_exp2f(sc[nk][qf][1]);
                    p2 = __builtin_amdgcn_exp2f(sc[nk][qf][2]);
                    p3 = __builtin_amdgcn_exp2f(sc[nk][qf][3]);
                } else {
                    p0 = __builtin_amdgcn_exp2f(sc[nk][qf][0] + m4.x);
                    p1 = __builtin_amdgcn_exp2f(sc[nk][qf][1] + m4.y);
                    p2 = __builtin_amdgcn_exp2f(sc[nk][qf][2] + m4.z);
                    p3 = __builtin_amdgcn_exp2f(sc[nk][qf][3] + m4.w);
                }
                lpart[qf] += (p0 + p1) + (p2 + p3);
                uint2 w; w.x = pkh(p0, p1); w.y = pkh(p2, p3);
                *(uint2*)&Ps[(64*qh + 16*qf + fr)*64 + pgw] = w;
            }
        }

        // O^T(partial) += V^T[:, slice] P[slice, :]  (V-frags: own slice only)
        const int gr = ((4*kh + fg) ^ frx) * 8;
        f16x8 vb[4], pa[4];
        #pragma unroll
        for (int df = 0; df < 4; ++df)
            vb[df] = *(const f16x8*)&Vs[cur][(16*df + fr)*64 + gr];
        #pragma unroll
        for (int qf = 0; qf < 4; ++qf)
            pa[qf] = *(const f16x8*)&Ps[(64*qh + 16*qf + fr)*64 + gr];
        __builtin_amdgcn_s_setprio(1);
        #pragma unroll
        for (int df = 0; df < 4; ++df)
            #pragma unroll
            for (int qf = 0; qf < 4; ++qf)
                o[df][qf] = __builtin_amdgcn_mfma_f32_16x16x32_f16(vb[df], pa[qf], o[df][qf], 0, 0, 0);
        __builtin_amdgcn_s_setprio(0);
        __syncthreads();   // drains prefetch (vmcnt) + protects K/V buffers
        cur ^= 1;
    }

    // ---- epilogue: cross-wave (kh) reduction through Ps-as-f32-scratch ----
    float* fx = (float*)Ps;                 // 4096 floats
    const int xl = qh*64 + lane;            // 0..127

    // R0: lpart
    if (kh) {
        #pragma unroll
        for (int qf = 0; qf < 4; ++qf) fx[xl*4 + qf] = lpart[qf];
    }
    __syncthreads();
    float inv[4];
    if (!kh) {
        #pragma unroll
        for (int qf = 0; qf < 4; ++qf) {
            float l = lpart[qf] + fx[xl*4 + qf];
            l += __shfl_xor(l, 16);
            l += __shfl_xor(l, 32);
            inv[qf] = 1.0f / l;
        }
    }
    __syncthreads();

    // R1/R2: o halves
    #pragma unroll
    for (int half = 0; half < 2; ++half) {
        if (kh) {
            #pragma unroll
            for (int d2 = 0; d2 < 2; ++d2)
                #pragma unroll
                for (int qf = 0; qf < 4; ++qf)
                    *(f32x4*)&fx[(xl*8 + d2*4 + qf)*4] = o[half*2 + d2][qf];
        }
        __syncthreads();
        if (!kh) {
            #pragma unroll
            for (int d2 = 0; d2 < 2; ++d2)
                #pragma unroll
                for (int qf = 0; qf < 4; ++qf) {
                    int df = half*2 + d2;
                    f32x4 r = o[df][qf] + *(const f32x4*)&fx[(xl*8 + d2*4 + qf)*4];
                    float iv = inv[qf];
                    uint2 w;
                    w.x = pkh(r[0]*iv, r[1]*iv);
                    w.y = pkh(r[2]*iv, r[3]*iv);
                    size_t base = ((size_t)b*SS + q0 + 64*qh + 16*qf + fr)*HH + h*HD;
                    *(uint2*)&cf[base + 16*df + 4*fg] = w;
                }
        }
        __syncthreads();
    }
}

extern "C" void kernel_launch(void* const* d_in, const int* in_sizes, int n_in,
                              void* d_out, int out_size, void* d_ws, size_t ws_size,
                              hipStream_t stream) {
    const float* x    = (const float*)d_in[0];
    const float* mask = (const float*)d_in[1];
    const float* Wq   = (const float*)d_in[2];
    const float* Wk   = (const float*)d_in[3];
    const float* Wv   = (const float*)d_in[4];
    const float* Wo   = (const float*)d_in[5];
    float* out = (float*)d_out;

    const size_t T = (size_t)MM * HH;            // 4M elements
    unsigned short* xf = (unsigned short*)d_ws;  // 8MB each
    unsigned short* wf = xf + T;                 // [4096][1024]: Wq,Wk,Wv,Wo rows
    unsigned short* qt = wf + T;
    unsigned short* kt = qt + T;
    unsigned short* vt = kt + T;
    float* ctab = (float*)(vt + T);
    float* stab = ctab + SS*32;
    float* mt   = stab + SS*32;                  // additive mask table [BB][SS]
    unsigned int* mfg = (unsigned int*)(mt + BB*SS);   // [BB][32] all-ones flags
    unsigned short* cf = xf;                     // ctx aliases xf (x consumed)

    prep<<<2048, 256, 0, stream>>>(x, mask, Wq, Wk, Wv, Wo, xf, wf, ctab, stab, mt, mfg);
    gemm3<0><<<dim3(MM/128, 3*HH/128), 256, 0, stream>>>(xf, wf, ctab, stab,
                                                         qt, kt, vt, nullptr);
    attn<<<512, 256, 0, stream>>>(qt, kt, vt, mt, mfg, cf);
    gemm3<1><<<dim3(MM/128, HH/128), 256, 0, stream>>>(cf, wf, nullptr, nullptr,
                                                       nullptr, nullptr, nullptr, out);
}

// Round 13
// 114.540 us; speedup vs baseline: 1.0435x; 1.0435x over previous
//
#include <hip/hip_runtime.h>
#include <math.h>

#define BB 2
#define SS 2048
#define HH 1024
#define NH 16
#define HD 64
#define MM (BB*SS)   // 4096

typedef __attribute__((ext_vector_type(8))) _Float16 f16x8;
typedef __attribute__((ext_vector_type(2))) __fp16 hf16x2;
typedef __attribute__((ext_vector_type(4))) float f32x4;
typedef __attribute__((ext_vector_type(16))) float f32x16;

// 0.125 (1/sqrt(64)) * log2(e), folded into Q at the projection epilogue
#define QSCALE 0.18033688011112042f

__device__ __forceinline__ unsigned short f2h(float f) {
    union { _Float16 h; unsigned short u; } c;
    c.h = (_Float16)f;
    return c.u;
}

// pack two floats to fp16x2 (RTZ) -> raw u32
__device__ __forceinline__ unsigned int pkh(float a, float b) {
    union { hf16x2 h; unsigned int u; } c;
    c.h = __builtin_amdgcn_cvt_pkrtz(a, b);
    return c.u;
}

__device__ __forceinline__ void gld16(const void* g, void* s) {
    __builtin_amdgcn_global_load_lds(
        (const __attribute__((address_space(1))) void*)g,
        (__attribute__((address_space(3))) void*)s, 16, 0, 0);
}

// ---------------- prep: cast x/W to fp16 + RoPE/mask tables + mask flags ----------------
__global__ __launch_bounds__(256) void prep(
    const float* __restrict__ x, const float* __restrict__ mask,
    const float* __restrict__ Wq, const float* __restrict__ Wk,
    const float* __restrict__ Wv, const float* __restrict__ Wo,
    unsigned short* __restrict__ xf, unsigned short* __restrict__ wf,
    float* __restrict__ ctab, float* __restrict__ stab, float* __restrict__ mt,
    unsigned int* __restrict__ mflag)
{
    int gtid = blockIdx.x * 256 + threadIdx.x;      // 2048*256 = 524288 threads
    if (gtid < SS * 32) {                            // RoPE table, f64 trig
        int s = gtid >> 5, i = gtid & 31;
        double invf = pow(10000.0, -(double)i / 32.0);
        double a = (double)s * invf;
        ctab[gtid] = (float)cos(a);
        stab[gtid] = (float)sin(a);
    }
    if (gtid < BB * SS) {                            // additive mask table (exp2 domain)
        float mv = mask[gtid];
        mt[gtid] = (1.0f - mv) * (-1.0e38f);
        unsigned long long bal = __ballot(mv == 1.0f);
        if ((threadIdx.x & 63) == 0)
            mflag[gtid >> 6] = (bal == ~0ull) ? 1u : 0u;
    }
    for (int it = gtid; it < 2097152; it += 524288) {   // 2M float4 items
        float4 v; unsigned short* d; size_t off;
        if (it < 1048576) {                              // x: [4096][1024]
            off = (size_t)it * 4;
            v = *(const float4*)(x + off);
            d = xf;
        } else {                                         // W concat rows: Wq,Wk,Wv,Wo
            off = (size_t)(it - 1048576) * 4;
            int row = (int)(off >> 10);
            const float* W = row < 1024 ? Wq : row < 2048 ? Wk : row < 3072 ? Wv : Wo;
            v = *(const float4*)(W + (((size_t)(row & 1023)) << 10) + (off & 1023));
            d = wf;
        }
        *(ushort4*)(d + off) = make_ushort4(f2h(v.x), f2h(v.y), f2h(v.z), f2h(v.w));
    }
}

// ---------------- fp16 MFMA GEMM (128x128 tile, BK=32, dbuf 32KB) ----------------
// (unchanged — verified 0 conflicts, 2-phase dbuf)
template<int MODE>
__global__ __launch_bounds__(256, 3) void gemm3(
    const unsigned short* __restrict__ Axf,
    const unsigned short* __restrict__ Wf,
    const float* __restrict__ ctab, const float* __restrict__ stab,
    unsigned short* __restrict__ qo, unsigned short* __restrict__ ko,
    unsigned short* __restrict__ vo, float* __restrict__ fout)
{
    __shared__ __align__(16) short lsA[2][128*32];
    __shared__ __align__(16) short lsB[2][128*32];

    const int t = threadIdx.x;
    const int m0 = blockIdx.x * 128;
    const int brow0 = (MODE == 0 ? 0 : 3072) + blockIdx.y * 128;
    const int lane = t & 63, wv = t >> 6;
    const int wm = (wv >> 1) * 64, wn = (wv & 1) * 64;
    const int fr = lane & 15, fg = lane >> 4;

    const int srow = t >> 2, pc = t & 3;
    const int scx = (pc ^ ((srow >> 1) & 3)) * 8;     // source col offset (shorts)
    const int lo  = srow * 32 + pc * 8;               // physical dest (shorts)
    const size_t gA0 = (size_t)(m0 + srow) * HH + scx;
    const size_t gA1 = (size_t)(m0 + 64 + srow) * HH + scx;
    const size_t gB0 = (size_t)(brow0 + srow) * HH + scx;
    const size_t gB1 = (size_t)(brow0 + 64 + srow) * HH + scx;

    f32x4 acc[4][4] = {};

#define STAGE(sel, kk) do { \
        gld16(Axf + gA0 + (kk), &lsA[sel][lo]);            \
        gld16(Wf  + gB0 + (kk), &lsB[sel][lo]);            \
        gld16(Axf + gA1 + (kk), &lsA[sel][lo + 64*32]);    \
        gld16(Wf  + gB1 + (kk), &lsB[sel][lo + 64*32]);    \
    } while (0)

    STAGE(0, 0);
    __syncthreads();

    int cur = 0;
    for (int k0 = 0; k0 < HH; k0 += 32) {
        if (k0 + 32 < HH) STAGE(cur ^ 1, k0 + 32);

        f16x8 ah[4], bh[4];
        const int swz = (fg ^ ((fr >> 1) & 3)) * 8;   // swizzled read granule
        #pragma unroll
        for (int mi = 0; mi < 4; ++mi)
            ah[mi] = *(const f16x8*)&lsA[cur][(wm + 16*mi + fr)*32 + swz];
        #pragma unroll
        for (int ni = 0; ni < 4; ++ni)
            bh[ni] = *(const f16x8*)&lsB[cur][(wn + 16*ni + fr)*32 + swz];

        __builtin_amdgcn_s_setprio(1);
        #pragma unroll
        for (int mi = 0; mi < 4; ++mi)
            #pragma unroll
            for (int ni = 0; ni < 4; ++ni)
                acc[mi][ni] = __builtin_amdgcn_mfma_f32_16x16x32_f16(ah[mi], bh[ni], acc[mi][ni], 0, 0, 0);
        __builtin_amdgcn_s_setprio(0);
        __syncthreads();
        cur ^= 1;
    }
#undef STAGE

    if (MODE == 0) {
        const int mat = brow0 >> 10;                 // 0=Q 1=K 2=V
        const int obase = (brow0 & 1023) + wn;       // 64-aligned
        const int h = obase >> 6;
        #pragma unroll
        for (int mi = 0; mi < 4; ++mi)
            #pragma unroll
            for (int rr = 0; rr < 4; ++rr) {
                int m = m0 + wm + 16*mi + 4*fg + rr;
                int b = m >> 11, s = m & (SS - 1);
                float v[4];
                #pragma unroll
                for (int ni = 0; ni < 4; ++ni) v[ni] = acc[mi][ni][rr];
                if (mat < 2) {                        // RoPE on Q,K
                    #pragma unroll
                    for (int ni = 0; ni < 2; ++ni) {
                        int i = 16*ni + fr;
                        float c = ctab[s*32 + i], sn = stab[s*32 + i];
                        float v1 = v[ni], v2 = v[ni + 2];
                        v[ni]     = v1*c - v2*sn;
                        v[ni + 2] = v2*c + v1*sn;
                    }
                }
                if (mat == 0) {                       // fold softmax scale into Q
                    #pragma unroll
                    for (int ni = 0; ni < 4; ++ni) v[ni] *= QSCALE;
                }
                size_t base = ((size_t)(b*NH + h) * SS + s) * HD;
                #pragma unroll
                for (int ni = 0; ni < 4; ++ni) {
                    int d = 16*ni + fr;
                    unsigned short hb = f2h(v[ni]);
                    if (mat == 0)      qo[base + d] = hb;
                    else if (mat == 1) ko[base + (d ^ ((s & 7) << 3))] = hb;
                    else {
                        size_t va = ((size_t)(b*NH + h) * HD + d) * SS
                                  + (s & ~63) + ((s & 63) ^ ((d & 7) << 3));
                        vo[va] = hb;
                    }
                }
            }
    } else {
        const int n0 = blockIdx.y * 128 + wn;
        #pragma unroll
        for (int mi = 0; mi < 4; ++mi)
            #pragma unroll
            for (int rr = 0; rr < 4; ++rr) {
                int m = m0 + wm + 16*mi + 4*fg + rr;
                #pragma unroll
                for (int ni = 0; ni < 4; ++ni)
                    fout[(size_t)m * HH + n0 + 16*ni + fr] = acc[mi][ni][rr];
            }
    }
}

// ---------------- flash attention, 32x32 MFMA + in-register P (T12) ----------------
// Grid 512 XCD-swizzled, 256 threads = 4 waves x 32 q. NO P LDS buffer:
// S^T = mfma_32x32x16(K,Q) gives col=lane&31=q, row=k; the PV B-operand
// (k=8*(lane>>5)+e) is built in-register with 16 cvt_pkrtz + 8
// v_permlane32_swap_b32 per tile. Word derivation: for k-chunk ki,
// setX = sc regs 8(ki&1)+{0..3} (u_t=0 rows), setY = +4 (u_t=1 rows);
// swap(A0,B0) leaves A0 = w0 (lanes<32: own setX@u0; >=32: setY@u0) and
// B0 = w2 (lanes<32: setX@u1; >=32: setY@u1); A1/B1 give w1/w3.
// K/V LDS reads: granule (2c+u)^(ql&7) cancels the global-side swizzle and
// is bank-conflict-free (each 8-lane phase covers 8 distinct granules).
// Per wave per tile: 8 K b128 + 8 V b128 only (the ingest floor).
__global__ __launch_bounds__(256, 2) void attn(
    const unsigned short* __restrict__ qg, const unsigned short* __restrict__ kg,
    const unsigned short* __restrict__ vtg, const float* __restrict__ mt,
    const unsigned int* __restrict__ mfl, unsigned short* __restrict__ cf)
{
    __shared__ __align__(16) short Ks[2][64*64];
    __shared__ __align__(16) short Vs[2][64*64];

    const int t = threadIdx.x, lane = t & 63, wv = t >> 6;   // wv 0..3
    const int ql = lane & 31;            // q (col) / matrix-row index
    const int u  = lane >> 5;            // lane half
    const int qx = ql & 7;               // swizzle bits
    const int flat = blockIdx.x;
    const int bh = (flat & 7) + ((flat >> 7) << 3);          // XCD-grouped
    const int q0 = ((flat >> 3) & 15) * 128;
    const int b = bh >> 4, h = bh & 15;

    const unsigned short* kgb = kg  + (size_t)bh*SS*HD;
    const unsigned short* vgb = vtg + (size_t)bh*HD*SS;
    const float* mtb = mt + (size_t)b*SS;
    const unsigned int* mfb = mfl + b*32;

    // Q B-frags: qa[dc]: q-row = q0+32wv+ql, d = 16dc + 8u + {0..7} (QSCALE folded)
    f16x8 qa[4];
    #pragma unroll
    for (int dc = 0; dc < 4; ++dc)
        qa[dc] = *(const f16x8*)&qg[((size_t)bh*SS + q0 + 32*wv + ql)*HD + 16*dc + 8*u];

    f32x16 o[2] = {};                    // O^T d-tiles (32d each) for q=ql
    float lpart = 0.f;

    const int srow = t >> 3, sg = t & 7;   // staging: 32 rows x 8 granules (x2)

    // prologue: stage tile 0
    gld16(kgb + (size_t)srow*HD + sg*8,      &Ks[0][srow*64 + sg*8]);
    gld16(kgb + (size_t)(32+srow)*HD + sg*8, &Ks[0][(32+srow)*64 + sg*8]);
    gld16(vgb + (size_t)srow*SS + sg*8,      &Vs[0][srow*64 + sg*8]);
    gld16(vgb + (size_t)(32+srow)*SS + sg*8, &Vs[0][(32+srow)*64 + sg*8]);
    __syncthreads();

    int cur = 0;
    for (int kt = 0; kt < SS/64; ++kt) {
        const int k0 = kt * 64;
        if (kt + 1 < SS/64) {                 // prefetch next tile
            const int kn = k0 + 64;
            gld16(kgb + (size_t)(kn+srow)*HD + sg*8,      &Ks[cur^1][srow*64 + sg*8]);
            gld16(kgb + (size_t)(kn+32+srow)*HD + sg*8,   &Ks[cur^1][(32+srow)*64 + sg*8]);
            gld16(vgb + (size_t)srow*SS + kn + sg*8,      &Vs[cur^1][srow*64 + sg*8]);
            gld16(vgb + (size_t)(32+srow)*SS + kn + sg*8, &Vs[cur^1][(32+srow)*64 + sg*8]);
        }
        const int fl = __builtin_amdgcn_readfirstlane(mfb[kt]);

        // K A-frags (8 b128) then QK^T: sc[ktl] = S^T[32ktl+..][q]
        f16x8 kb[2][4];
        #pragma unroll
        for (int ktl = 0; ktl < 2; ++ktl)
            #pragma unroll
            for (int dc = 0; dc < 4; ++dc)
                kb[ktl][dc] = *(const f16x8*)&Ks[cur][(32*ktl + ql)*64 + ((2*dc + u) ^ qx)*8];

        f32x16 sc[2] = {};
        __builtin_amdgcn_s_setprio(1);
        #pragma unroll
        for (int dc = 0; dc < 4; ++dc)
            #pragma unroll
            for (int ktl = 0; ktl < 2; ++ktl)
                sc[ktl] = __builtin_amdgcn_mfma_f32_32x32x16_f16(kb[ktl][dc], qa[dc], sc[ktl], 0, 0, 0);
        __builtin_amdgcn_s_setprio(0);

        // V A-frags (8 b128, independent of sc — issue before the VALU phase)
        f16x8 vb[2][4];
        #pragma unroll
        for (int dt = 0; dt < 2; ++dt)
            #pragma unroll
            for (int ki = 0; ki < 4; ++ki)
                vb[dt][ki] = *(const f16x8*)&Vs[cur][(32*dt + ql)*64 + ((2*ki + u) ^ qx)*8];

        // P = 2^(s [+ madd]) in fp32 regs; accumulate row-sum
        if (fl) {                              // unmasked tile (common path)
            #pragma unroll
            for (int ktl = 0; ktl < 2; ++ktl)
                #pragma unroll
                for (int r = 0; r < 16; ++r) {
                    float p = __builtin_amdgcn_exp2f(sc[ktl][r]);
                    sc[ktl][r] = p;
                    lpart += p;
                }
        } else {
            #pragma unroll
            for (int ktl = 0; ktl < 2; ++ktl)
                #pragma unroll
                for (int g = 0; g < 4; ++g) {
                    float4 m4 = *(const float4*)&mtb[k0 + 32*ktl + 8*g + 4*u];
                    #pragma unroll
                    for (int j = 0; j < 4; ++j) {
                        float p = __builtin_amdgcn_exp2f(sc[ktl][4*g + j] + (&m4.x)[j]);
                        sc[ktl][4*g + j] = p;
                        lpart += p;
                    }
                }
        }

        // PV: per k-chunk ki build P B-frag via cvt_pk + permlane32_swap
        __builtin_amdgcn_s_setprio(1);
        #pragma unroll
        for (int ki = 0; ki < 4; ++ki) {
            const int ktl = ki >> 1;
            const int R0 = 8 * (ki & 1);
            unsigned int A0 = pkh(sc[ktl][R0+0], sc[ktl][R0+1]);
            unsigned int A1 = pkh(sc[ktl][R0+2], sc[ktl][R0+3]);
            unsigned int B0 = pkh(sc[ktl][R0+4], sc[ktl][R0+5]);
            unsigned int B1 = pkh(sc[ktl][R0+6], sc[ktl][R0+7]);
            asm volatile("v_permlane32_swap_b32 %0, %1" : "+v"(A0), "+v"(B0));
            asm volatile("v_permlane32_swap_b32 %0, %1" : "+v"(A1), "+v"(B1));
            union { unsigned int w[4]; f16x8 v; } pf;
            pf.w[0] = A0; pf.w[1] = A1; pf.w[2] = B0; pf.w[3] = B1;
            #pragma unroll
            for (int dt = 0; dt < 2; ++dt)
                o[dt] = __builtin_amdgcn_mfma_f32_32x32x16_f16(vb[dt][ki], pf.v, o[dt], 0, 0, 0);
        }
        __builtin_amdgcn_s_setprio(0);
        __syncthreads();   // drains prefetch (vmcnt) + protects K/V buffers
        cur ^= 1;
    }

    // epilogue: l over both lane halves, normalize, packed stores
    float l = lpart + __shfl_xor(lpart, 32);
    float inv = 1.0f / l;
    size_t base = ((size_t)b*SS + q0 + 32*wv + ql)*HH + h*HD;
    #pragma unroll
    for (int dt = 0; dt < 2; ++dt)
        #pragma unroll
        for (int g = 0; g < 4; ++g) {
            uint2 w;
            w.x = pkh(o[dt][4*g+0]*inv, o[dt][4*g+1]*inv);
            w.y = pkh(o[dt][4*g+2]*inv, o[dt][4*g+3]*inv);
            *(uint2*)&cf[base + 32*dt + 8*g + 4*u] = w;
        }
}

extern "C" void kernel_launch(void* const* d_in, const int* in_sizes, int n_in,
                              void* d_out, int out_size, void* d_ws, size_t ws_size,
                              hipStream_t stream) {
    const float* x    = (const float*)d_in[0];
    const float* mask = (const float*)d_in[1];
    const float* Wq   = (const float*)d_in[2];
    const float* Wk   = (const float*)d_in[3];
    const float* Wv   = (const float*)d_in[4];
    const float* Wo   = (const float*)d_in[5];
    float* out = (float*)d_out;

    const size_t T = (size_t)MM * HH;            // 4M elements
    unsigned short* xf = (unsigned short*)d_ws;  // 8MB each
    unsigned short* wf = xf + T;                 // [4096][1024]: Wq,Wk,Wv,Wo rows
    unsigned short* qt = wf + T;
    unsigned short* kt = qt + T;
    unsigned short* vt = kt + T;
    float* ctab = (float*)(vt + T);
    float* stab = ctab + SS*32;
    float* mt   = stab + SS*32;                  // additive mask table [BB][SS]
    unsigned int* mfg = (unsigned int*)(mt + BB*SS);   // [BB][32] all-ones flags
    unsigned short* cf = xf;                     // ctx aliases xf (x consumed)

    prep<<<2048, 256, 0, stream>>>(x, mask, Wq, Wk, Wv, Wo, xf, wf, ctab, stab, mt, mfg);
    gemm3<0><<<dim3(MM/128, 3*HH/128), 256, 0, stream>>>(xf, wf, ctab, stab,
                                                         qt, kt, vt, nullptr);
    attn<<<512, 256, 0, stream>>>(qt, kt, vt, mt, mfg, cf);
    gemm3<1><<<dim3(MM/128, HH/128), 256, 0, stream>>>(cf, wf, nullptr, nullptr,
                                                       nullptr, nullptr, nullptr, out);
}